// Round 2
// baseline (506.142 us; speedup 1.0000x reference)
//
#include <hip/hip_runtime.h>

#define NN 25600      // nodes = 160*160
#define HH 160
#define WW 160
#define C2 256

// ---- converted fp32 tensor offsets inside ws (floats) ----
#define O_X      0L
#define O_WID    3276800L
#define O_WIN    3309568L
#define O_WGAT   3342336L
#define O_ASRC   3473408L
#define O_ADST   3473920L
#define O_GBIAS  3474432L
#define O_BNG    3474944L
#define O_BNB    3475456L
#define O_BNM    3475968L
#define O_BNV    3476480L
#define O_WOUT   3476992L
#define O_SEW1   3542528L
#define O_SEB1   3558912L
#define O_SEW2   3558976L
#define O_SEB2   3575360L
#define O_END    3575616L   // divisible by 64

__device__ __forceinline__ float b2f(unsigned short u) {
    union { unsigned int ui; float f; } v; v.ui = ((unsigned int)u) << 16; return v.f;
}
__device__ __forceinline__ unsigned short f2b(float f) {
    union { float f; unsigned int u; } v; v.f = f;
    unsigned int u = v.u;
    unsigned int r = (u + 0x7FFFu + ((u >> 16) & 1u)) >> 16;
    return (unsigned short)r;
}

// ---------------------------------------------------------------------------
// Detect input dtype: read first 256 halfwords of x as bf16. If inputs are
// really fp32, the low-half words have random exponent bytes -> wild values.
// flag = 1 -> inputs (and output) are fp32; flag = 0 -> bf16.
// ---------------------------------------------------------------------------
__global__ void detect_kernel(const unsigned short* __restrict__ x, int* __restrict__ flag) {
    __shared__ int s;
    const int t = threadIdx.x;
    if (t == 0) s = 0;
    __syncthreads();
    float v = b2f(x[t]);
    bool wild = !(fabsf(v) < 1e6f);   // catches NaN too
    if (wild) atomicOr(&s, 1);
    __syncthreads();
    if (t == 0) *flag = s;
}

// ---------------------------------------------------------------------------
// Convert all float inputs to fp32 in ws (identity copy if already fp32).
// ---------------------------------------------------------------------------
__global__ __launch_bounds__(256) void convert_kernel(
    const void* px, const void* pwid, const void* pwin, const void* pwgat,
    const void* pasrc, const void* padst, const void* pgbias,
    const void* pbng, const void* pbnb, const void* pbnm, const void* pbnv,
    const void* pwout, const void* psew1, const void* pseb1,
    const void* psew2, const void* pseb2,
    float* __restrict__ dst, const int* __restrict__ flag)
{
    const bool f32 = (*flag != 0);
    for (long i = (long)blockIdx.x * 256 + threadIdx.x; i < O_END; i += (long)gridDim.x * 256) {
        const void* s; long o;
        if      (i < O_WID)   { s = px;    o = i - O_X; }
        else if (i < O_WIN)   { s = pwid;  o = i - O_WID; }
        else if (i < O_WGAT)  { s = pwin;  o = i - O_WIN; }
        else if (i < O_ASRC)  { s = pwgat; o = i - O_WGAT; }
        else if (i < O_ADST)  { s = pasrc; o = i - O_ASRC; }
        else if (i < O_GBIAS) { s = padst; o = i - O_ADST; }
        else if (i < O_BNG)   { s = pgbias;o = i - O_GBIAS; }
        else if (i < O_BNB)   { s = pbng;  o = i - O_BNG; }
        else if (i < O_BNM)   { s = pbnb;  o = i - O_BNB; }
        else if (i < O_BNV)   { s = pbnm;  o = i - O_BNM; }
        else if (i < O_WOUT)  { s = pbnv;  o = i - O_BNV; }
        else if (i < O_SEW1)  { s = pwout; o = i - O_WOUT; }
        else if (i < O_SEB1)  { s = psew1; o = i - O_SEW1; }
        else if (i < O_SEW2)  { s = pseb1; o = i - O_SEB1; }
        else if (i < O_SEB2)  { s = psew2; o = i - O_SEW2; }
        else                  { s = pseb2; o = i - O_SEB2; }
        float v = f32 ? ((const float*)s)[o] : b2f(((const unsigned short*)s)[o]);
        dst[i] = v;
    }
}

// ---------------------------------------------------------------------------
// GEMM: xf[m][o] = sum_k x[k][m] * w_in[o][k];  idb likewise with w_id.
// x: fp32 [128][25600] (channel-major), w: fp32 [256][128] row-major.
// Outputs fp32 node-major [25600][256]. Tile 64x64, BK=32, 256 thr, 4x4 micro.
// ---------------------------------------------------------------------------
__global__ __launch_bounds__(256) void gemm_x2_kernel(
    const float* __restrict__ x,
    const float* __restrict__ w_in,
    const float* __restrict__ w_id,
    float* __restrict__ xf,
    float* __restrict__ idb)
{
    __shared__ float As[32][68];
    __shared__ float Bi[32][68];
    __shared__ float Bd[32][68];
    const int tid = threadIdx.x;
    const int tx = tid & 15, ty = tid >> 4;
    const int m0 = blockIdx.x * 64;
    const int o0 = blockIdx.y * 64;

    float ai[4][4], ad[4][4];
#pragma unroll
    for (int i = 0; i < 4; ++i)
#pragma unroll
        for (int j = 0; j < 4; ++j) { ai[i][j] = 0.f; ad[i][j] = 0.f; }

    for (int k0 = 0; k0 < 128; k0 += 32) {
#pragma unroll
        for (int c = tid; c < 512; c += 256) {
            int k = c >> 4, nq = c & 15;
            float4 v = *(const float4*)(x + (long)(k0 + k) * NN + m0 + nq * 4);
            As[k][nq * 4 + 0] = v.x;
            As[k][nq * 4 + 1] = v.y;
            As[k][nq * 4 + 2] = v.z;
            As[k][nq * 4 + 3] = v.w;
        }
#pragma unroll
        for (int c = tid; c < 512; c += 256) {
            int o = c >> 3, kq = c & 7;
            float4 vi = *(const float4*)(w_in + (o0 + o) * 128 + k0 + kq * 4);
            float4 vd = *(const float4*)(w_id + (o0 + o) * 128 + k0 + kq * 4);
            Bi[kq * 4 + 0][o] = vi.x; Bd[kq * 4 + 0][o] = vd.x;
            Bi[kq * 4 + 1][o] = vi.y; Bd[kq * 4 + 1][o] = vd.y;
            Bi[kq * 4 + 2][o] = vi.z; Bd[kq * 4 + 2][o] = vd.z;
            Bi[kq * 4 + 3][o] = vi.w; Bd[kq * 4 + 3][o] = vd.w;
        }
        __syncthreads();
#pragma unroll
        for (int kk = 0; kk < 32; ++kk) {
            float4 av = *(const float4*)&As[kk][ty * 4];
            float4 bv = *(const float4*)&Bi[kk][tx * 4];
            float4 cv = *(const float4*)&Bd[kk][tx * 4];
            float a[4] = {av.x, av.y, av.z, av.w};
            float b[4] = {bv.x, bv.y, bv.z, bv.w};
            float d[4] = {cv.x, cv.y, cv.z, cv.w};
#pragma unroll
            for (int i = 0; i < 4; ++i)
#pragma unroll
                for (int j = 0; j < 4; ++j) {
                    ai[i][j] += a[i] * b[j];
                    ad[i][j] += a[i] * d[j];
                }
        }
        __syncthreads();
    }
#pragma unroll
    for (int i = 0; i < 4; ++i) {
        int m = m0 + ty * 4 + i;
        *(float4*)&xf[(long)m * C2 + o0 + tx * 4] = make_float4(ai[i][0], ai[i][1], ai[i][2], ai[i][3]);
        *(float4*)&idb[(long)m * C2 + o0 + tx * 4] = make_float4(ad[i][0], ad[i][1], ad[i][2], ad[i][3]);
    }
}

// ---------------------------------------------------------------------------
// GEMM: C[m][o] = sum_k A[m][k] * W[o][k].  A fp32 [25600][256], W fp32 [256][256].
// ---------------------------------------------------------------------------
__global__ __launch_bounds__(256) void gemm_nn_kernel(
    const float* __restrict__ A,
    const float* __restrict__ W,
    float* __restrict__ C)
{
    __shared__ float As[32][68];
    __shared__ float Bs[32][68];
    const int tid = threadIdx.x;
    const int tx = tid & 15, ty = tid >> 4;
    const int m0 = blockIdx.x * 64;
    const int o0 = blockIdx.y * 64;

    float acc[4][4];
#pragma unroll
    for (int i = 0; i < 4; ++i)
#pragma unroll
        for (int j = 0; j < 4; ++j) acc[i][j] = 0.f;

    for (int k0 = 0; k0 < 256; k0 += 32) {
#pragma unroll
        for (int c = tid; c < 512; c += 256) {
            int m = c >> 3, kq = c & 7;
            float4 v = *(const float4*)(A + (long)(m0 + m) * C2 + k0 + kq * 4);
            As[kq * 4 + 0][m] = v.x;
            As[kq * 4 + 1][m] = v.y;
            As[kq * 4 + 2][m] = v.z;
            As[kq * 4 + 3][m] = v.w;
        }
#pragma unroll
        for (int c = tid; c < 512; c += 256) {
            int o = c >> 3, kq = c & 7;
            float4 v = *(const float4*)(W + (o0 + o) * C2 + k0 + kq * 4);
            Bs[kq * 4 + 0][o] = v.x;
            Bs[kq * 4 + 1][o] = v.y;
            Bs[kq * 4 + 2][o] = v.z;
            Bs[kq * 4 + 3][o] = v.w;
        }
        __syncthreads();
#pragma unroll
        for (int kk = 0; kk < 32; ++kk) {
            float4 av = *(const float4*)&As[kk][ty * 4];
            float4 bv = *(const float4*)&Bs[kk][tx * 4];
            float a[4] = {av.x, av.y, av.z, av.w};
            float b[4] = {bv.x, bv.y, bv.z, bv.w};
#pragma unroll
            for (int i = 0; i < 4; ++i)
#pragma unroll
                for (int j = 0; j < 4; ++j) acc[i][j] += a[i] * b[j];
        }
        __syncthreads();
    }
#pragma unroll
    for (int i = 0; i < 4; ++i) {
        int m = m0 + ty * 4 + i;
        *(float4*)&C[(long)m * C2 + o0 + tx * 4] =
            make_float4(acc[i][0], acc[i][1], acc[i][2], acc[i][3]);
    }
}

// ---------------------------------------------------------------------------
// Attention coefficients: al_s[n][hd] = sum_d h[n][hd*32+d]*a_src[hd][d].
// ---------------------------------------------------------------------------
__global__ __launch_bounds__(256) void attn_kernel(
    const float* __restrict__ h,
    const float* __restrict__ a_src,
    const float* __restrict__ a_dst,
    float* __restrict__ al_s, float* __restrict__ al_d)
{
    __shared__ float asv[256], adv[256];
    const int tid = threadIdx.x;
    asv[tid] = a_src[tid];
    adv[tid] = a_dst[tid];
    __syncthreads();
    const int g = blockIdx.x * 256 + tid;        // over N*8
    const int n = g >> 3, hd = g & 7;
    const float* hp = h + (long)n * C2 + hd * 32;
    const float* ap = &asv[hd * 32];
    const float* dp = &adv[hd * 32];
    float ss = 0.f, sd = 0.f;
#pragma unroll
    for (int d = 0; d < 32; d += 4) {
        float4 v = *(const float4*)(hp + d);
        ss += v.x * ap[d] + v.y * ap[d + 1] + v.z * ap[d + 2] + v.w * ap[d + 3];
        sd += v.x * dp[d] + v.y * dp[d + 1] + v.z * dp[d + 2] + v.w * dp[d + 3];
    }
    al_s[g] = ss;
    al_d[g] = sd;
}

// ---------------------------------------------------------------------------
// Per-destination segment-softmax aggregation + bias + BN + ReLU + residual.
// One block per node; thread = channel; <=11 incoming stencil edges (incl self).
// ---------------------------------------------------------------------------
__global__ __launch_bounds__(256) void aggregate_kernel(
    const float* __restrict__ h,
    const float* __restrict__ al_s,
    const float* __restrict__ al_d,
    const float* __restrict__ bias,
    const float* __restrict__ gamma,
    const float* __restrict__ beta,
    const float* __restrict__ mean,
    const float* __restrict__ var,
    float* __restrict__ xf)
{
    const int SI[11] = { 1, 1, 1, 0, 0, -1, -1, -1, -2,  0, 0};
    const int SJ[11] = { 1, 0,-1, 1,-1,  1,  0, -1,  0, -2, 0};
    __shared__ float es[11][8];

    const int n = blockIdx.x;
    const int i = n / WW, j = n % WW;
    const int c = threadIdx.x;
    const int hd = c >> 5;

    int srcn[11]; bool ok[11];
#pragma unroll
    for (int k = 0; k < 11; ++k) {
        int si = i + SI[k], sj = j + SJ[k];
        ok[k] = (si >= 0) & (si < HH) & (sj >= 0) & (sj < WW);
        srcn[k] = si * WW + sj;
    }
    if (c < 88) {
        int k = c >> 3, hh = c & 7;
        es[k][hh] = ok[k] ? al_s[srcn[k] * 8 + hh] : 0.f;
    }
    __syncthreads();

    const float ald = al_d[n * 8 + hd];
    float e[11];
    float mx = -1e30f;
#pragma unroll
    for (int k = 0; k < 11; ++k) {
        if (ok[k]) {
            float v = es[k][hd] + ald;
            v = v > 0.f ? v : 0.2f * v;          // leaky_relu(0.2)
            e[k] = v;
            mx = fmaxf(mx, v);
        }
    }
    float denom = 0.f;
#pragma unroll
    for (int k = 0; k < 11; ++k) {
        if (ok[k]) {
            float p = __expf(e[k] - mx);
            e[k] = p;
            denom += p;
        }
    }
    const float inv = 1.f / (denom + 1e-16f);
    float acc = 0.f;
#pragma unroll
    for (int k = 0; k < 11; ++k) {
        if (ok[k]) acc += e[k] * inv * h[(long)srcn[k] * C2 + c];
    }
    float g = acc + bias[c];
    float sc = gamma[c] * rsqrtf(var[c] + 1e-5f);
    g = (g - mean[c]) * sc + beta[c];
    g = fmaxf(g, 0.f);
    xf[(long)n * C2 + c] = g + xf[(long)n * C2 + c];
}

// ---------------------------------------------------------------------------
// SE: channel sums (atomic partials), then the two tiny FC layers.
// ---------------------------------------------------------------------------
__global__ __launch_bounds__(256) void se_mean_kernel(
    const float* __restrict__ y, float* __restrict__ means)
{
    const int b = blockIdx.x;     // 256 blocks x 100 nodes
    const int t = threadIdx.x;    // channel
    float acc = 0.f;
    const int nb = b * 100;
    for (int nrel = 0; nrel < 100; ++nrel) acc += y[(long)(nb + nrel) * C2 + t];
    atomicAdd(&means[t], acc);
}

__global__ __launch_bounds__(256) void se_vec_kernel(
    const float* __restrict__ means,
    const float* __restrict__ se_w1, const float* __restrict__ se_b1,
    const float* __restrict__ se_w2, const float* __restrict__ se_b2,
    float* __restrict__ svec)
{
    __shared__ float mv[256];
    __shared__ float hv[64];
    const int t = threadIdx.x;
    mv[t] = means[t] * (1.0f / 25600.0f);
    __syncthreads();
    if (t < 64) {
        float s = se_b1[t];
        for (int cc = 0; cc < 256; ++cc) s += se_w1[t * 256 + cc] * mv[cc];
        hv[t] = fmaxf(s, 0.f);
    }
    __syncthreads();
    float s = se_b2[t];
    for (int k = 0; k < 64; ++k) s += se_w2[t * 64 + k] * hv[k];
    svec[t] = 1.0f / (1.0f + __expf(-s));
}

// ---------------------------------------------------------------------------
// Final: out[c][n] = y[n][c]*s[c] + id[n][c]  (LDS-transposed; dtype by flag)
// ---------------------------------------------------------------------------
__global__ __launch_bounds__(256) void final_kernel(
    const float* __restrict__ y,
    const float* __restrict__ idb,
    const float* __restrict__ svec,
    void* __restrict__ outp,
    const int* __restrict__ flag)
{
    __shared__ float T[64][65];
    const bool f32o = (*flag != 0);
    const int t = threadIdx.x;
    const int n0 = blockIdx.x * 64, c0 = blockIdx.y * 64;
#pragma unroll
    for (int it = 0; it < 16; ++it) {
        int e = t + it * 256;
        int nn = e >> 6, cc = e & 63;
        long idx = (long)(n0 + nn) * C2 + c0 + cc;
        T[cc][nn] = y[idx] * svec[c0 + cc] + idb[idx];
    }
    __syncthreads();
#pragma unroll
    for (int it = 0; it < 16; ++it) {
        int e = t + it * 256;
        int cc = e >> 6, nn = e & 63;
        long idx = (long)(c0 + cc) * NN + n0 + nn;
        float v = T[cc][nn];
        if (f32o) ((float*)outp)[idx] = v;
        else      ((unsigned short*)outp)[idx] = f2b(v);
    }
}

extern "C" void kernel_launch(void* const* d_in, const int* in_sizes, int n_in,
                              void* d_out, int out_size, void* d_ws, size_t ws_size,
                              hipStream_t stream) {
    float* ws = (float*)d_ws;
    float* cvt   = ws;                       // O_END floats of converted inputs
    float* xf    = ws + O_END;               // 25600*256
    float* hb    = xf + 6553600;             // h for hops, then y (reused)
    float* idb   = hb + 6553600;             // identity, node-major
    float* als   = idb + 6553600;            // 25600*8
    float* ald   = als + 204800;
    float* means = ald + 204800;             // 256
    float* svec  = means + 256;              // 256
    int*   flag  = (int*)(svec + 256);

    const float* x_c     = cvt + O_X;
    const float* w_id_c  = cvt + O_WID;
    const float* w_in_c  = cvt + O_WIN;
    const float* w_gat_c = cvt + O_WGAT;
    const float* a_src_c = cvt + O_ASRC;
    const float* a_dst_c = cvt + O_ADST;
    const float* gbias_c = cvt + O_GBIAS;
    const float* bng_c   = cvt + O_BNG;
    const float* bnb_c   = cvt + O_BNB;
    const float* bnm_c   = cvt + O_BNM;
    const float* bnv_c   = cvt + O_BNV;
    const float* w_out_c = cvt + O_WOUT;
    const float* sew1_c  = cvt + O_SEW1;
    const float* seb1_c  = cvt + O_SEB1;
    const float* sew2_c  = cvt + O_SEW2;
    const float* seb2_c  = cvt + O_SEB2;

    hipMemsetAsync(means, 0, 256 * sizeof(float), stream);

    dim3 b256(256);
    dim3 gtile(NN / 64, C2 / 64);      // 400 x 4

    detect_kernel<<<1, b256, 0, stream>>>((const unsigned short*)d_in[0], flag);
    convert_kernel<<<2048, b256, 0, stream>>>(
        d_in[0], d_in[1], d_in[2], d_in[3], d_in[4], d_in[5], d_in[6], d_in[7],
        d_in[8], d_in[9], d_in[10], d_in[11], d_in[12], d_in[13], d_in[14], d_in[15],
        cvt, flag);

    gemm_x2_kernel<<<gtile, b256, 0, stream>>>(x_c, w_in_c, w_id_c, xf, idb);

    for (int l = 0; l < 2; ++l) {
        gemm_nn_kernel<<<gtile, b256, 0, stream>>>(xf, w_gat_c + l * 65536, hb);
        attn_kernel<<<NN * 8 / 256, b256, 0, stream>>>(hb, a_src_c + l * 256, a_dst_c + l * 256, als, ald);
        aggregate_kernel<<<NN, b256, 0, stream>>>(hb, als, ald,
            gbias_c + l * 256, bng_c + l * 256, bnb_c + l * 256,
            bnm_c + l * 256, bnv_c + l * 256, xf);
    }

    gemm_nn_kernel<<<gtile, b256, 0, stream>>>(xf, w_out_c, hb);
    se_mean_kernel<<<256, b256, 0, stream>>>(hb, means);
    se_vec_kernel<<<1, b256, 0, stream>>>(means, sew1_c, seb1_c, sew2_c, seb2_c, svec);
    final_kernel<<<gtile, b256, 0, stream>>>(hb, idb, svec, d_out, flag);
}

// Round 3
// 282.387 us; speedup vs baseline: 1.7924x; 1.7924x over previous
//
#include <hip/hip_runtime.h>

#define NN 25600      // nodes = 160*160
#define HH 160
#define WW 160
#define C2 256

// ---- converted fp32 tensor offsets inside ws (floats) ----
#define O_X      0L
#define O_WID    3276800L
#define O_WIN    3309568L
#define O_WGAT   3342336L
#define O_ASRC   3473408L
#define O_ADST   3473920L
#define O_GBIAS  3474432L
#define O_BNG    3474944L
#define O_BNB    3475456L
#define O_BNM    3475968L
#define O_BNV    3476480L
#define O_WOUT   3476992L
#define O_SEW1   3542528L
#define O_SEB1   3558912L
#define O_SEW2   3558976L
#define O_SEB2   3575360L
#define O_END    3575616L   // divisible by 64

// ---- bf16 weight pack offsets (ushorts) ----
#define B_WIN   0
#define B_WID   32768
#define B_WGAT  65536      // 2 layers x 65536
#define B_WOUT  196608
#define B_WEND  262144

typedef __attribute__((ext_vector_type(8))) short bfrag;   // 8 bf16 (4 VGPRs)
typedef __attribute__((ext_vector_type(4))) float ffrag;   // 4 fp32 acc

__device__ __forceinline__ float b2f(unsigned short u) {
    union { unsigned int ui; float f; } v; v.ui = ((unsigned int)u) << 16; return v.f;
}
__device__ __forceinline__ unsigned short f2b(float f) {
    union { float f; unsigned int u; } v; v.f = f;
    unsigned int u = v.u;
    unsigned int r = (u + 0x7FFFu + ((u >> 16) & 1u)) >> 16;
    return (unsigned short)r;
}

// ---------------------------------------------------------------------------
// Detect input dtype (bf16 vs fp32) from first 256 halfwords of x.
// ---------------------------------------------------------------------------
__global__ void detect_kernel(const unsigned short* __restrict__ x, int* __restrict__ flag) {
    __shared__ int s;
    const int t = threadIdx.x;
    if (t == 0) s = 0;
    __syncthreads();
    float v = b2f(x[t]);
    bool wild = !(fabsf(v) < 1e6f);
    if (wild) atomicOr(&s, 1);
    __syncthreads();
    if (t == 0) *flag = s;
}

// ---------------------------------------------------------------------------
// Convert all float inputs to fp32 in ws.
// ---------------------------------------------------------------------------
__global__ __launch_bounds__(256) void convert_kernel(
    const void* px, const void* pwid, const void* pwin, const void* pwgat,
    const void* pasrc, const void* padst, const void* pgbias,
    const void* pbng, const void* pbnb, const void* pbnm, const void* pbnv,
    const void* pwout, const void* psew1, const void* pseb1,
    const void* psew2, const void* pseb2,
    float* __restrict__ dst, const int* __restrict__ flag)
{
    const bool f32 = (*flag != 0);
    for (long i = (long)blockIdx.x * 256 + threadIdx.x; i < O_END; i += (long)gridDim.x * 256) {
        const void* s; long o;
        if      (i < O_WID)   { s = px;    o = i - O_X; }
        else if (i < O_WIN)   { s = pwid;  o = i - O_WID; }
        else if (i < O_WGAT)  { s = pwin;  o = i - O_WIN; }
        else if (i < O_ASRC)  { s = pwgat; o = i - O_WGAT; }
        else if (i < O_ADST)  { s = pasrc; o = i - O_ASRC; }
        else if (i < O_GBIAS) { s = padst; o = i - O_ADST; }
        else if (i < O_BNG)   { s = pgbias;o = i - O_GBIAS; }
        else if (i < O_BNB)   { s = pbng;  o = i - O_BNG; }
        else if (i < O_BNM)   { s = pbnb;  o = i - O_BNB; }
        else if (i < O_BNV)   { s = pbnm;  o = i - O_BNM; }
        else if (i < O_WOUT)  { s = pbnv;  o = i - O_BNV; }
        else if (i < O_SEW1)  { s = pwout; o = i - O_WOUT; }
        else if (i < O_SEB1)  { s = psew1; o = i - O_SEW1; }
        else if (i < O_SEW2)  { s = pseb1; o = i - O_SEB1; }
        else if (i < O_SEB2)  { s = psew2; o = i - O_SEW2; }
        else                  { s = pseb2; o = i - O_SEB2; }
        float v = f32 ? ((const float*)s)[o] : b2f(((const unsigned short*)s)[o]);
        dst[i] = v;
    }
}

// ---------------------------------------------------------------------------
// Pack GEMM weights to bf16.
// ---------------------------------------------------------------------------
__global__ __launch_bounds__(256) void prep_w_kernel(
    const float* __restrict__ cvt, unsigned short* __restrict__ wb)
{
    for (int i = blockIdx.x * 256 + threadIdx.x; i < B_WEND; i += gridDim.x * 256) {
        long o;
        if      (i < B_WID)   o = O_WIN  + i;
        else if (i < B_WGAT)  o = O_WID  + (i - B_WID);
        else if (i < B_WOUT)  o = O_WGAT + (i - B_WGAT);
        else                  o = O_WOUT + (i - B_WOUT);
        wb[i] = f2b(cvt[o]);
    }
}

// ---------------------------------------------------------------------------
// Transpose x: fp32 [128][25600] channel-major -> bf16 [25600][128] node-major.
// ---------------------------------------------------------------------------
__global__ __launch_bounds__(256) void transpose_x_kernel(
    const float* __restrict__ xsrc, unsigned short* __restrict__ xT)
{
    __shared__ unsigned short T[64 * 136];
    const int t = threadIdx.x;
    const int n0 = blockIdx.x * 64;
    const int nl = t & 63;
#pragma unroll
    for (int i = 0; i < 32; ++i) {
        int c = i * 4 + (t >> 6);
        T[nl * 136 + c] = f2b(xsrc[(long)c * NN + n0 + nl]);
    }
    __syncthreads();
#pragma unroll
    for (int i = 0; i < 4; ++i) {
        int n = t >> 2, c0 = (t & 3) * 32 + i * 8;
        uint4 v = *(const uint4*)&T[n * 136 + c0];
        *(uint4*)(xT + (long)(n0 + n) * 128 + c0) = v;
    }
}

// ---------------------------------------------------------------------------
// MFMA GEMM (dual-B): xf[m][o]=sum_k A[m][k]Wi[o][k]; idb likewise with Wd.
// A bf16 [25600][128]; Wi,Wd bf16 [256][128]. Tile 128x64, 4 waves.
// Also writes xf16 (bf16 copy of xf).
// ---------------------------------------------------------------------------
__global__ __launch_bounds__(256) void mfma_gemm_x2_kernel(
    const unsigned short* __restrict__ A16,
    const unsigned short* __restrict__ Wi16,
    const unsigned short* __restrict__ Wd16,
    float* __restrict__ xf, unsigned short* __restrict__ xf16,
    float* __restrict__ idb)
{
    __shared__ unsigned short As[128 * 40];
    __shared__ unsigned short Bi[64 * 40];
    __shared__ unsigned short Bd[64 * 40];
    const int tid = threadIdx.x;
    const int m0 = blockIdx.x * 128, o0 = blockIdx.y * 64;
    const int lane = tid & 63, wv = tid >> 6;
    const int wm = wv >> 1, wn = wv & 1;
    const int lr = lane & 15, quad = lane >> 4;

    ffrag ai[4][2], ad[4][2];
#pragma unroll
    for (int mt = 0; mt < 4; ++mt)
#pragma unroll
        for (int nt = 0; nt < 2; ++nt) { ai[mt][nt] = (ffrag){0,0,0,0}; ad[mt][nt] = (ffrag){0,0,0,0}; }

    for (int k0 = 0; k0 < 128; k0 += 32) {
#pragma unroll
        for (int c = tid; c < 512; c += 256) {
            int row = c >> 2, q = c & 3;
            uint4 v = *(const uint4*)(A16 + (long)(m0 + row) * 128 + k0 + q * 8);
            *(uint4*)&As[row * 40 + q * 8] = v;
        }
        {
            int row = tid >> 2, q = tid & 3;
            uint4 vi = *(const uint4*)(Wi16 + (long)(o0 + row) * 128 + k0 + q * 8);
            uint4 vd = *(const uint4*)(Wd16 + (long)(o0 + row) * 128 + k0 + q * 8);
            *(uint4*)&Bi[row * 40 + q * 8] = vi;
            *(uint4*)&Bd[row * 40 + q * 8] = vd;
        }
        __syncthreads();
        bfrag a[4], bi[2], bd[2];
#pragma unroll
        for (int mt = 0; mt < 4; ++mt)
            a[mt] = *(const bfrag*)&As[(wm * 64 + mt * 16 + lr) * 40 + quad * 8];
#pragma unroll
        for (int nt = 0; nt < 2; ++nt) {
            bi[nt] = *(const bfrag*)&Bi[(wn * 32 + nt * 16 + lr) * 40 + quad * 8];
            bd[nt] = *(const bfrag*)&Bd[(wn * 32 + nt * 16 + lr) * 40 + quad * 8];
        }
#pragma unroll
        for (int mt = 0; mt < 4; ++mt)
#pragma unroll
            for (int nt = 0; nt < 2; ++nt) {
                ai[mt][nt] = __builtin_amdgcn_mfma_f32_16x16x32_bf16(a[mt], bi[nt], ai[mt][nt], 0, 0, 0);
                ad[mt][nt] = __builtin_amdgcn_mfma_f32_16x16x32_bf16(a[mt], bd[nt], ad[mt][nt], 0, 0, 0);
            }
        __syncthreads();
    }
#pragma unroll
    for (int mt = 0; mt < 4; ++mt)
#pragma unroll
        for (int nt = 0; nt < 2; ++nt)
#pragma unroll
            for (int r = 0; r < 4; ++r) {
                int m = m0 + wm * 64 + mt * 16 + quad * 4 + r;
                int o = o0 + wn * 32 + nt * 16 + lr;
                float vi = ai[mt][nt][r];
                xf[(long)m * C2 + o] = vi;
                xf16[(long)m * C2 + o] = f2b(vi);
                idb[(long)m * C2 + o] = ad[mt][nt][r];
            }
}

// ---------------------------------------------------------------------------
// MFMA GEMM: C[m][o] = sum_k A[m][k] W[o][k]. A bf16 [25600][256], W bf16 [256][256].
// ---------------------------------------------------------------------------
__global__ __launch_bounds__(256) void mfma_gemm_nn_kernel(
    const unsigned short* __restrict__ A16,
    const unsigned short* __restrict__ W16,
    float* __restrict__ C)
{
    __shared__ unsigned short As[128 * 40];
    __shared__ unsigned short Bs[64 * 40];
    const int tid = threadIdx.x;
    const int m0 = blockIdx.x * 128, o0 = blockIdx.y * 64;
    const int lane = tid & 63, wv = tid >> 6;
    const int wm = wv >> 1, wn = wv & 1;
    const int lr = lane & 15, quad = lane >> 4;

    ffrag acc[4][2];
#pragma unroll
    for (int mt = 0; mt < 4; ++mt)
#pragma unroll
        for (int nt = 0; nt < 2; ++nt) acc[mt][nt] = (ffrag){0,0,0,0};

    for (int k0 = 0; k0 < 256; k0 += 32) {
#pragma unroll
        for (int c = tid; c < 512; c += 256) {
            int row = c >> 2, q = c & 3;
            uint4 v = *(const uint4*)(A16 + (long)(m0 + row) * 256 + k0 + q * 8);
            *(uint4*)&As[row * 40 + q * 8] = v;
        }
        {
            int row = tid >> 2, q = tid & 3;
            uint4 v = *(const uint4*)(W16 + (long)(o0 + row) * 256 + k0 + q * 8);
            *(uint4*)&Bs[row * 40 + q * 8] = v;
        }
        __syncthreads();
        bfrag a[4], b[2];
#pragma unroll
        for (int mt = 0; mt < 4; ++mt)
            a[mt] = *(const bfrag*)&As[(wm * 64 + mt * 16 + lr) * 40 + quad * 8];
#pragma unroll
        for (int nt = 0; nt < 2; ++nt)
            b[nt] = *(const bfrag*)&Bs[(wn * 32 + nt * 16 + lr) * 40 + quad * 8];
#pragma unroll
        for (int mt = 0; mt < 4; ++mt)
#pragma unroll
            for (int nt = 0; nt < 2; ++nt)
                acc[mt][nt] = __builtin_amdgcn_mfma_f32_16x16x32_bf16(a[mt], b[nt], acc[mt][nt], 0, 0, 0);
        __syncthreads();
    }
#pragma unroll
    for (int mt = 0; mt < 4; ++mt)
#pragma unroll
        for (int nt = 0; nt < 2; ++nt)
#pragma unroll
            for (int r = 0; r < 4; ++r) {
                int m = m0 + wm * 64 + mt * 16 + quad * 4 + r;
                int o = o0 + wn * 32 + nt * 16 + lr;
                C[(long)m * C2 + o] = acc[mt][nt][r];
            }
}

// ---------------------------------------------------------------------------
// Attention coefficients: al_s[n][hd] = sum_d h[n][hd*32+d]*a_src[hd][d].
// ---------------------------------------------------------------------------
__global__ __launch_bounds__(256) void attn_kernel(
    const float* __restrict__ h,
    const float* __restrict__ a_src,
    const float* __restrict__ a_dst,
    float* __restrict__ al_s, float* __restrict__ al_d)
{
    __shared__ float asv[256], adv[256];
    const int tid = threadIdx.x;
    asv[tid] = a_src[tid];
    adv[tid] = a_dst[tid];
    __syncthreads();
    const int g = blockIdx.x * 256 + tid;        // over N*8
    const int n = g >> 3, hd = g & 7;
    const float* hp = h + (long)n * C2 + hd * 32;
    const float* ap = &asv[hd * 32];
    const float* dp = &adv[hd * 32];
    float ss = 0.f, sd = 0.f;
#pragma unroll
    for (int d = 0; d < 32; d += 4) {
        float4 v = *(const float4*)(hp + d);
        ss += v.x * ap[d] + v.y * ap[d + 1] + v.z * ap[d + 2] + v.w * ap[d + 3];
        sd += v.x * dp[d] + v.y * dp[d + 1] + v.z * dp[d + 2] + v.w * dp[d + 3];
    }
    al_s[g] = ss;
    al_d[g] = sd;
}

// ---------------------------------------------------------------------------
// Aggregation: 4 nodes/block, 64 threads/node, 4 channels/thread (float4).
// Softmax computed once per (node,head) in LDS; then 11-tap weighted gather
// + bias + BN + ReLU + residual. Writes xf (fp32) and xf16 (bf16).
// ---------------------------------------------------------------------------
__global__ __launch_bounds__(256) void aggregate_kernel(
    const float* __restrict__ h,
    const float* __restrict__ al_s,
    const float* __restrict__ al_d,
    const float* __restrict__ bias,
    const float* __restrict__ gamma,
    const float* __restrict__ beta,
    const float* __restrict__ mean,
    const float* __restrict__ var,
    float* __restrict__ xf, unsigned short* __restrict__ xf16)
{
    const int SI[11] = { 1, 1, 1, 0, 0, -1, -1, -1, -2,  0, 0};
    const int SJ[11] = { 1, 0,-1, 1,-1,  1,  0, -1,  0, -2, 0};
    __shared__ float es[4][11][8];
    __shared__ float alpha[4][11][8];

    const int t = threadIdx.x;
    const int ln = t >> 6;            // local node 0..3
    const int l = t & 63;
    const int n = blockIdx.x * 4 + ln;
    const int i = n / WW, j = n % WW;

    // stage neighbor al_s (invalid -> -1e30 so its softmax weight is exactly 0)
    for (int idx = l; idx < 88; idx += 64) {
        int k = idx >> 3, hh = idx & 7;
        int si = i + SI[k], sj = j + SJ[k];
        bool ok = (si >= 0) & (si < HH) & (sj >= 0) & (sj < WW);
        es[ln][k][hh] = ok ? al_s[(si * WW + sj) * 8 + hh] : -1e30f;
    }
    __syncthreads();

    if (l < 8) {
        const int hd = l;
        const float ald = al_d[n * 8 + hd];
        float e[11];
        float mx = -1e30f;
#pragma unroll
        for (int k = 0; k < 11; ++k) {
            float v = es[ln][k][hd] + ald;
            v = v > 0.f ? v : 0.2f * v;          // leaky_relu(0.2); -1e30 stays huge-neg
            e[k] = v;
            mx = fmaxf(mx, v);
        }
        float denom = 0.f;
#pragma unroll
        for (int k = 0; k < 11; ++k) {
            float p = __expf(e[k] - mx);         // underflows to 0 for invalid taps
            e[k] = p;
            denom += p;
        }
        const float inv = 1.f / (denom + 1e-16f);
#pragma unroll
        for (int k = 0; k < 11; ++k) alpha[ln][k][hd] = e[k] * inv;
    }
    __syncthreads();

    const int c4 = l * 4;
    const int hd = c4 >> 5;
    int srcn[11];
#pragma unroll
    for (int k = 0; k < 11; ++k) {
        int si = i + SI[k], sj = j + SJ[k];
        bool ok = (si >= 0) & (si < HH) & (sj >= 0) & (sj < WW);
        srcn[k] = ok ? si * WW + sj : n;         // clamp; alpha==0 for invalid
    }
    float ax = 0.f, ay = 0.f, az = 0.f, aw = 0.f;
#pragma unroll
    for (int k = 0; k < 11; ++k) {
        float a = alpha[ln][k][hd];
        float4 hv = *(const float4*)(h + (long)srcn[k] * C2 + c4);
        ax += a * hv.x; ay += a * hv.y; az += a * hv.z; aw += a * hv.w;
    }
    float4 bz = *(const float4*)(bias + c4);
    float4 gm = *(const float4*)(gamma + c4);
    float4 bt = *(const float4*)(beta + c4);
    float4 mn = *(const float4*)(mean + c4);
    float4 vr = *(const float4*)(var + c4);
    float4 res = *(const float4*)(xf + (long)n * C2 + c4);
    float g0 = fmaxf((ax + bz.x - mn.x) * (gm.x * rsqrtf(vr.x + 1e-5f)) + bt.x, 0.f) + res.x;
    float g1 = fmaxf((ay + bz.y - mn.y) * (gm.y * rsqrtf(vr.y + 1e-5f)) + bt.y, 0.f) + res.y;
    float g2 = fmaxf((az + bz.z - mn.z) * (gm.z * rsqrtf(vr.z + 1e-5f)) + bt.z, 0.f) + res.z;
    float g3 = fmaxf((aw + bz.w - mn.w) * (gm.w * rsqrtf(vr.w + 1e-5f)) + bt.w, 0.f) + res.w;
    *(float4*)(xf + (long)n * C2 + c4) = make_float4(g0, g1, g2, g3);
    ushort4 o16; o16.x = f2b(g0); o16.y = f2b(g1); o16.z = f2b(g2); o16.w = f2b(g3);
    *(ushort4*)(xf16 + (long)n * C2 + c4) = o16;
}

// ---------------------------------------------------------------------------
// SE: channel sums (atomic partials), then the two tiny FC layers.
// ---------------------------------------------------------------------------
__global__ __launch_bounds__(256) void se_mean_kernel(
    const float* __restrict__ y, float* __restrict__ means)
{
    const int b = blockIdx.x;
    const int t = threadIdx.x;
    float acc = 0.f;
    const int nb = b * 100;
    for (int nrel = 0; nrel < 100; ++nrel) acc += y[(long)(nb + nrel) * C2 + t];
    atomicAdd(&means[t], acc);
}

__global__ __launch_bounds__(256) void se_vec_kernel(
    const float* __restrict__ means,
    const float* __restrict__ se_w1, const float* __restrict__ se_b1,
    const float* __restrict__ se_w2, const float* __restrict__ se_b2,
    float* __restrict__ svec)
{
    __shared__ float mv[256];
    __shared__ float hv[64];
    const int t = threadIdx.x;
    mv[t] = means[t] * (1.0f / 25600.0f);
    __syncthreads();
    if (t < 64) {
        float s = se_b1[t];
        for (int cc = 0; cc < 256; ++cc) s += se_w1[t * 256 + cc] * mv[cc];
        hv[t] = fmaxf(s, 0.f);
    }
    __syncthreads();
    float s = se_b2[t];
    for (int k = 0; k < 64; ++k) s += se_w2[t * 64 + k] * hv[k];
    svec[t] = 1.0f / (1.0f + __expf(-s));
}

// ---------------------------------------------------------------------------
// Final: out[c][n] = y[n][c]*s[c] + id[n][c]  (LDS-transposed; dtype by flag)
// ---------------------------------------------------------------------------
__global__ __launch_bounds__(256) void final_kernel(
    const float* __restrict__ y,
    const float* __restrict__ idb,
    const float* __restrict__ svec,
    void* __restrict__ outp,
    const int* __restrict__ flag)
{
    __shared__ float T[64][65];
    const bool f32o = (*flag != 0);
    const int t = threadIdx.x;
    const int n0 = blockIdx.x * 64, c0 = blockIdx.y * 64;
#pragma unroll
    for (int it = 0; it < 16; ++it) {
        int e = t + it * 256;
        int nn = e >> 6, cc = e & 63;
        long idx = (long)(n0 + nn) * C2 + c0 + cc;
        T[cc][nn] = y[idx] * svec[c0 + cc] + idb[idx];
    }
    __syncthreads();
#pragma unroll
    for (int it = 0; it < 16; ++it) {
        int e = t + it * 256;
        int cc = e >> 6, nn = e & 63;
        long idx = (long)(c0 + cc) * NN + n0 + nn;
        float v = T[cc][nn];
        if (f32o) ((float*)outp)[idx] = v;
        else      ((unsigned short*)outp)[idx] = f2b(v);
    }
}

extern "C" void kernel_launch(void* const* d_in, const int* in_sizes, int n_in,
                              void* d_out, int out_size, void* d_ws, size_t ws_size,
                              hipStream_t stream) {
    float* ws = (float*)d_ws;
    float* cvt   = ws;                       // O_END floats of converted inputs
    float* xf    = ws + O_END;               // 25600*256 fp32
    float* hb    = xf + 6553600;             // h for hops, then y
    float* idb   = hb + 6553600;             // identity, node-major fp32
    float* als   = idb + 6553600;            // 25600*8
    float* ald   = als + 204800;
    float* means = ald + 204800;             // 256
    float* svec  = means + 256;              // 256
    int*   flag  = (int*)(svec + 256);
    unsigned short* wb16 = (unsigned short*)(svec + 512);     // 262144 ushorts
    unsigned short* xf16 = (unsigned short*)cvt;              // aliases cvt x-region (freed after transpose)
    unsigned short* xT16 = (unsigned short*)hb;               // aliases hb (freed before first gemm_nn)

    const float* x_c     = cvt + O_X;
    const float* a_src_c = cvt + O_ASRC;
    const float* a_dst_c = cvt + O_ADST;
    const float* gbias_c = cvt + O_GBIAS;
    const float* bng_c   = cvt + O_BNG;
    const float* bnb_c   = cvt + O_BNB;
    const float* bnm_c   = cvt + O_BNM;
    const float* bnv_c   = cvt + O_BNV;
    const float* sew1_c  = cvt + O_SEW1;
    const float* seb1_c  = cvt + O_SEB1;
    const float* sew2_c  = cvt + O_SEW2;
    const float* seb2_c  = cvt + O_SEB2;

    hipMemsetAsync(means, 0, 256 * sizeof(float), stream);

    dim3 b256(256);
    dim3 gmfma(NN / 128, C2 / 64);     // 200 x 4
    dim3 gfin(NN / 64, C2 / 64);       // 400 x 4

    detect_kernel<<<1, b256, 0, stream>>>((const unsigned short*)d_in[0], flag);
    convert_kernel<<<2048, b256, 0, stream>>>(
        d_in[0], d_in[1], d_in[2], d_in[3], d_in[4], d_in[5], d_in[6], d_in[7],
        d_in[8], d_in[9], d_in[10], d_in[11], d_in[12], d_in[13], d_in[14], d_in[15],
        cvt, flag);

    transpose_x_kernel<<<NN / 64, b256, 0, stream>>>(x_c, xT16);
    prep_w_kernel<<<256, b256, 0, stream>>>(cvt, wb16);

    mfma_gemm_x2_kernel<<<gmfma, b256, 0, stream>>>(
        xT16, wb16 + B_WIN, wb16 + B_WID, xf, xf16, idb);

    for (int l = 0; l < 2; ++l) {
        mfma_gemm_nn_kernel<<<gmfma, b256, 0, stream>>>(xf16, wb16 + B_WGAT + l * 65536, hb);
        attn_kernel<<<NN * 8 / 256, b256, 0, stream>>>(hb, a_src_c + l * 256, a_dst_c + l * 256, als, ald);
        aggregate_kernel<<<NN / 4, b256, 0, stream>>>(hb, als, ald,
            gbias_c + l * 256, bng_c + l * 256, bnb_c + l * 256,
            bnm_c + l * 256, bnv_c + l * 256, xf, xf16);
    }

    mfma_gemm_nn_kernel<<<gmfma, b256, 0, stream>>>(xf16, wb16 + B_WOUT, hb);
    se_mean_kernel<<<256, b256, 0, stream>>>(hb, means);
    se_vec_kernel<<<1, b256, 0, stream>>>(means, sew1_c, seb1_c, sew2_c, seb2_c, svec);
    final_kernel<<<gfin, b256, 0, stream>>>(hb, idb, svec, d_out, flag);
}

// Round 4
// 274.038 us; speedup vs baseline: 1.8470x; 1.0305x over previous
//
#include <hip/hip_runtime.h>

#define NN 25600      // nodes = 160*160
#define HH 160
#define WW 160
#define C2 256

// ---- small fp32 tensor offsets inside cvt (floats) ----
#define S_ASRC   0
#define S_ADST   512
#define S_GBIAS  1024
#define S_BNG    1536
#define S_BNB    2048
#define S_BNM    2560
#define S_BNV    3072
#define S_SEW1   3584
#define S_SEB1   19968
#define S_SEW2   20032
#define S_SEB2   36416
#define S_END    36672

// ---- bf16 weight pack offsets (ushorts) ----
#define B_WIN   0
#define B_WID   32768
#define B_WGAT  65536      // 2 layers x 65536
#define B_WOUT  196608
#define B_WEND  262144

typedef __attribute__((ext_vector_type(8))) short bfrag;   // 8 bf16 (4 VGPRs)
typedef __attribute__((ext_vector_type(4))) float ffrag;   // 4 fp32 acc

__device__ __forceinline__ float b2f(unsigned short u) {
    union { unsigned int ui; float f; } v; v.ui = ((unsigned int)u) << 16; return v.f;
}
__device__ __forceinline__ unsigned short f2b(float f) {
    union { float f; unsigned int u; } v; v.f = f;
    unsigned int u = v.u;
    unsigned int r = (u + 0x7FFFu + ((u >> 16) & 1u)) >> 16;
    return (unsigned short)r;
}
__device__ __forceinline__ float lo16f(unsigned int w) {
    union { unsigned int ui; float f; } v; v.ui = w << 16; return v.f;
}
__device__ __forceinline__ float hi16f(unsigned int w) {
    union { unsigned int ui; float f; } v; v.ui = w & 0xFFFF0000u; return v.f;
}

// ---------------------------------------------------------------------------
// Detect input dtype (bf16 vs fp32) from first 256 halfwords of x.
// flag=1 -> fp32 inputs/outputs.
// ---------------------------------------------------------------------------
__global__ void detect_kernel(const unsigned short* __restrict__ x, int* __restrict__ flag) {
    __shared__ int s;
    const int t = threadIdx.x;
    if (t == 0) s = 0;
    __syncthreads();
    float v = b2f(x[t]);
    bool wild = !(fabsf(v) < 1e6f);
    if (wild) atomicOr(&s, 1);
    __syncthreads();
    if (t == 0) *flag = s;
}

// ---------------------------------------------------------------------------
// Convert the small float tensors to fp32 in cvt.
// ---------------------------------------------------------------------------
__global__ __launch_bounds__(256) void convert_small_kernel(
    const void* pasrc, const void* padst, const void* pgbias,
    const void* pbng, const void* pbnb, const void* pbnm, const void* pbnv,
    const void* psew1, const void* pseb1, const void* psew2, const void* pseb2,
    float* __restrict__ dst, const int* __restrict__ flag)
{
    const bool f32 = (*flag != 0);
    for (int i = blockIdx.x * 256 + threadIdx.x; i < S_END; i += gridDim.x * 256) {
        const void* s; int o;
        if      (i < S_ADST)  { s = pasrc; o = i - S_ASRC; }
        else if (i < S_GBIAS) { s = padst; o = i - S_ADST; }
        else if (i < S_BNG)   { s = pgbias;o = i - S_GBIAS; }
        else if (i < S_BNB)   { s = pbng;  o = i - S_BNG; }
        else if (i < S_BNM)   { s = pbnb;  o = i - S_BNB; }
        else if (i < S_BNV)   { s = pbnm;  o = i - S_BNM; }
        else if (i < S_SEW1)  { s = pbnv;  o = i - S_BNV; }
        else if (i < S_SEB1)  { s = psew1; o = i - S_SEW1; }
        else if (i < S_SEW2)  { s = pseb1; o = i - S_SEB1; }
        else if (i < S_SEB2)  { s = psew2; o = i - S_SEW2; }
        else                  { s = pseb2; o = i - S_SEB2; }
        dst[i] = f32 ? ((const float*)s)[o] : b2f(((const unsigned short*)s)[o]);
    }
}

// ---------------------------------------------------------------------------
// Pack GEMM weights to bf16 (reads raw inputs, dtype by flag).
// ---------------------------------------------------------------------------
__global__ __launch_bounds__(256) void prep_w_kernel(
    const void* pwin, const void* pwid, const void* pwgat, const void* pwout,
    unsigned short* __restrict__ wb, const int* __restrict__ flag)
{
    const bool f32 = (*flag != 0);
    for (int i = blockIdx.x * 256 + threadIdx.x; i < B_WEND; i += gridDim.x * 256) {
        const void* s; int o;
        if      (i < B_WID)   { s = pwin;  o = i - B_WIN; }
        else if (i < B_WGAT)  { s = pwid;  o = i - B_WID; }
        else if (i < B_WOUT)  { s = pwgat; o = i - B_WGAT; }
        else                  { s = pwout; o = i - B_WOUT; }
        wb[i] = f32 ? f2b(((const float*)s)[o]) : ((const unsigned short*)s)[o];
    }
}

// ---------------------------------------------------------------------------
// Transpose x: [128][25600] channel-major (fp32 or bf16) -> bf16 [25600][128].
// ---------------------------------------------------------------------------
__global__ __launch_bounds__(256) void transpose_x_kernel(
    const void* __restrict__ xsrc, unsigned short* __restrict__ xT,
    const int* __restrict__ flag)
{
    __shared__ unsigned short T[64 * 136];
    const bool f32 = (*flag != 0);
    const int t = threadIdx.x;
    const int n0 = blockIdx.x * 64;
    const int nl = t & 63;
#pragma unroll
    for (int i = 0; i < 32; ++i) {
        int c = i * 4 + (t >> 6);
        long idx = (long)c * NN + n0 + nl;
        unsigned short v = f32 ? f2b(((const float*)xsrc)[idx])
                               : ((const unsigned short*)xsrc)[idx];
        T[nl * 136 + c] = v;
    }
    __syncthreads();
#pragma unroll
    for (int i = 0; i < 4; ++i) {
        int n = t >> 2, c0 = (t & 3) * 32 + i * 8;
        uint4 v = *(const uint4*)&T[n * 136 + c0];
        *(uint4*)(xT + (long)(n0 + n) * 128 + c0) = v;
    }
}

// ---------------------------------------------------------------------------
// MFMA GEMM (dual-B, K=128): xf=A@Wi^T (fp32+bf16), idb16=A@Wd^T (bf16).
// ---------------------------------------------------------------------------
__global__ __launch_bounds__(256) void mfma_gemm_x2_kernel(
    const unsigned short* __restrict__ A16,
    const unsigned short* __restrict__ Wi16,
    const unsigned short* __restrict__ Wd16,
    float* __restrict__ xf, unsigned short* __restrict__ xf16,
    unsigned short* __restrict__ idb16)
{
    __shared__ unsigned short As[128 * 40];
    __shared__ unsigned short Bi[64 * 40];
    __shared__ unsigned short Bd[64 * 40];
    const int tid = threadIdx.x;
    const int m0 = blockIdx.x * 128, o0 = blockIdx.y * 64;
    const int lane = tid & 63, wv = tid >> 6;
    const int wm = wv >> 1, wn = wv & 1;
    const int lr = lane & 15, quad = lane >> 4;

    ffrag ai[4][2], ad[4][2];
#pragma unroll
    for (int mt = 0; mt < 4; ++mt)
#pragma unroll
        for (int nt = 0; nt < 2; ++nt) { ai[mt][nt] = (ffrag){0,0,0,0}; ad[mt][nt] = (ffrag){0,0,0,0}; }

    for (int k0 = 0; k0 < 128; k0 += 32) {
#pragma unroll
        for (int c = tid; c < 512; c += 256) {
            int row = c >> 2, q = c & 3;
            uint4 v = *(const uint4*)(A16 + (long)(m0 + row) * 128 + k0 + q * 8);
            *(uint4*)&As[row * 40 + q * 8] = v;
        }
        {
            int row = tid >> 2, q = tid & 3;
            uint4 vi = *(const uint4*)(Wi16 + (long)(o0 + row) * 128 + k0 + q * 8);
            uint4 vd = *(const uint4*)(Wd16 + (long)(o0 + row) * 128 + k0 + q * 8);
            *(uint4*)&Bi[row * 40 + q * 8] = vi;
            *(uint4*)&Bd[row * 40 + q * 8] = vd;
        }
        __syncthreads();
        bfrag a[4], bi[2], bd[2];
#pragma unroll
        for (int mt = 0; mt < 4; ++mt)
            a[mt] = *(const bfrag*)&As[(wm * 64 + mt * 16 + lr) * 40 + quad * 8];
#pragma unroll
        for (int nt = 0; nt < 2; ++nt) {
            bi[nt] = *(const bfrag*)&Bi[(wn * 32 + nt * 16 + lr) * 40 + quad * 8];
            bd[nt] = *(const bfrag*)&Bd[(wn * 32 + nt * 16 + lr) * 40 + quad * 8];
        }
#pragma unroll
        for (int mt = 0; mt < 4; ++mt)
#pragma unroll
            for (int nt = 0; nt < 2; ++nt) {
                ai[mt][nt] = __builtin_amdgcn_mfma_f32_16x16x32_bf16(a[mt], bi[nt], ai[mt][nt], 0, 0, 0);
                ad[mt][nt] = __builtin_amdgcn_mfma_f32_16x16x32_bf16(a[mt], bd[nt], ad[mt][nt], 0, 0, 0);
            }
        __syncthreads();
    }
#pragma unroll
    for (int mt = 0; mt < 4; ++mt)
#pragma unroll
        for (int nt = 0; nt < 2; ++nt)
#pragma unroll
            for (int r = 0; r < 4; ++r) {
                int m = m0 + wm * 64 + mt * 16 + quad * 4 + r;
                int o = o0 + wn * 32 + nt * 16 + lr;
                float vi = ai[mt][nt][r];
                xf[(long)m * C2 + o] = vi;
                xf16[(long)m * C2 + o] = f2b(vi);
                idb16[(long)m * C2 + o] = f2b(ad[mt][nt][r]);
            }
}

// ---------------------------------------------------------------------------
// MFMA GEMM (K=256): C16 = A@W^T in bf16. mode=1: also emit al_s/al_d from
// the fp32 accumulators (head = 2*blockIdx.y + wn spans exactly this wave's
// 32 columns; butterfly-reduce over the 16-lane column group).
// ---------------------------------------------------------------------------
__global__ __launch_bounds__(256) void mfma_gemm_nn_kernel(
    const unsigned short* __restrict__ A16,
    const unsigned short* __restrict__ W16,
    unsigned short* __restrict__ C16,
    const float* __restrict__ asrc, const float* __restrict__ adst,
    float* __restrict__ al_s, float* __restrict__ al_d,
    int mode)
{
    __shared__ unsigned short As[128 * 40];
    __shared__ unsigned short Bs[64 * 40];
    const int tid = threadIdx.x;
    const int m0 = blockIdx.x * 128, o0 = blockIdx.y * 64;
    const int lane = tid & 63, wv = tid >> 6;
    const int wm = wv >> 1, wn = wv & 1;
    const int lr = lane & 15, quad = lane >> 4;

    ffrag acc[4][2];
#pragma unroll
    for (int mt = 0; mt < 4; ++mt)
#pragma unroll
        for (int nt = 0; nt < 2; ++nt) acc[mt][nt] = (ffrag){0,0,0,0};

    for (int k0 = 0; k0 < 256; k0 += 32) {
#pragma unroll
        for (int c = tid; c < 512; c += 256) {
            int row = c >> 2, q = c & 3;
            uint4 v = *(const uint4*)(A16 + (long)(m0 + row) * 256 + k0 + q * 8);
            *(uint4*)&As[row * 40 + q * 8] = v;
        }
        {
            int row = tid >> 2, q = tid & 3;
            uint4 v = *(const uint4*)(W16 + (long)(o0 + row) * 256 + k0 + q * 8);
            *(uint4*)&Bs[row * 40 + q * 8] = v;
        }
        __syncthreads();
        bfrag a[4], b[2];
#pragma unroll
        for (int mt = 0; mt < 4; ++mt)
            a[mt] = *(const bfrag*)&As[(wm * 64 + mt * 16 + lr) * 40 + quad * 8];
#pragma unroll
        for (int nt = 0; nt < 2; ++nt)
            b[nt] = *(const bfrag*)&Bs[(wn * 32 + nt * 16 + lr) * 40 + quad * 8];
#pragma unroll
        for (int mt = 0; mt < 4; ++mt)
#pragma unroll
            for (int nt = 0; nt < 2; ++nt)
                acc[mt][nt] = __builtin_amdgcn_mfma_f32_16x16x32_bf16(a[mt], b[nt], acc[mt][nt], 0, 0, 0);
        __syncthreads();
    }
#pragma unroll
    for (int mt = 0; mt < 4; ++mt)
#pragma unroll
        for (int nt = 0; nt < 2; ++nt)
#pragma unroll
            for (int r = 0; r < 4; ++r) {
                int m = m0 + wm * 64 + mt * 16 + quad * 4 + r;
                int o = o0 + wn * 32 + nt * 16 + lr;
                C16[(long)m * C2 + o] = f2b(acc[mt][nt][r]);
            }
    if (mode) {
        const int head = blockIdx.y * 2 + wn;
        const float as0 = asrc[head * 32 + lr],      as1 = asrc[head * 32 + 16 + lr];
        const float ad0 = adst[head * 32 + lr],      ad1 = adst[head * 32 + 16 + lr];
#pragma unroll
        for (int mt = 0; mt < 4; ++mt)
#pragma unroll
            for (int r = 0; r < 4; ++r) {
                float ps = acc[mt][0][r] * as0 + acc[mt][1][r] * as1;
                float pd = acc[mt][0][r] * ad0 + acc[mt][1][r] * ad1;
#pragma unroll
                for (int sh = 1; sh < 16; sh <<= 1) {
                    ps += __shfl_xor(ps, sh);
                    pd += __shfl_xor(pd, sh);
                }
                if (lr == 0) {
                    int m = m0 + wm * 64 + mt * 16 + quad * 4 + r;
                    al_s[m * 8 + head] = ps;
                    al_d[m * 8 + head] = pd;
                }
            }
    }
}

// ---------------------------------------------------------------------------
// Aggregation: 8 nodes/block, 32 thr/node, 8 bf16 channels/thread.
// Softmax once per (node,head) in LDS; 11-tap weighted gather of bf16 h;
// bias+BN+ReLU+residual. Updates xf (fp32) and writes xf16 (bf16).
// ---------------------------------------------------------------------------
__global__ __launch_bounds__(256) void aggregate_kernel(
    const unsigned short* __restrict__ h16,
    const float* __restrict__ al_s,
    const float* __restrict__ al_d,
    const float* __restrict__ bias,
    const float* __restrict__ gamma,
    const float* __restrict__ beta,
    const float* __restrict__ mean,
    const float* __restrict__ var,
    float* __restrict__ xf, unsigned short* __restrict__ xf16)
{
    const int SI[11] = { 1, 1, 1, 0, 0, -1, -1, -1, -2,  0, 0};
    const int SJ[11] = { 1, 0,-1, 1,-1,  1,  0, -1,  0, -2, 0};
    __shared__ float es[8][11][8];
    __shared__ float alpha[8][11][8];

    const int t = threadIdx.x;
    const int ln = t >> 5;            // local node 0..7
    const int l = t & 31;
    const int n = blockIdx.x * 8 + ln;
    const int i = n / WW, j = n % WW;

    // stage neighbor al_s for the block's 8 nodes (704 entries)
    for (int idx = t; idx < 704; idx += 256) {
        int lln = idx / 88, rem = idx - lln * 88;
        int k = rem >> 3, hh = rem & 7;
        int nn2 = blockIdx.x * 8 + lln;
        int ii = nn2 / WW, jj = nn2 - ii * WW;
        int si = ii + SI[k], sj = jj + SJ[k];
        bool okk = (si >= 0) & (si < HH) & (sj >= 0) & (sj < WW);
        es[lln][k][hh] = okk ? al_s[(si * WW + sj) * 8 + hh] : -1e30f;
    }
    __syncthreads();

    if (l < 8) {
        const int hd = l;
        const float ald = al_d[n * 8 + hd];
        float e[11];
        float mx = -1e30f;
#pragma unroll
        for (int k = 0; k < 11; ++k) {
            float v = es[ln][k][hd] + ald;
            v = v > 0.f ? v : 0.2f * v;          // leaky_relu(0.2)
            e[k] = v;
            mx = fmaxf(mx, v);
        }
        float denom = 0.f;
#pragma unroll
        for (int k = 0; k < 11; ++k) {
            float p = __expf(e[k] - mx);         // underflows to 0 for invalid taps
            e[k] = p;
            denom += p;
        }
        const float inv = 1.f / (denom + 1e-16f);
#pragma unroll
        for (int k = 0; k < 11; ++k) alpha[ln][k][hd] = e[k] * inv;
    }
    __syncthreads();

    const int c8 = l * 8;
    const int hd = l >> 2;
    int srcn[11];
#pragma unroll
    for (int k = 0; k < 11; ++k) {
        int si = i + SI[k], sj = j + SJ[k];
        bool ok = (si >= 0) & (si < HH) & (sj >= 0) & (sj < WW);
        srcn[k] = ok ? si * WW + sj : n;         // clamp; alpha==0 for invalid
    }
    float a0=0.f,a1=0.f,a2=0.f,a3=0.f,a4=0.f,a5=0.f,a6=0.f,a7=0.f;
#pragma unroll
    for (int k = 0; k < 11; ++k) {
        float al = alpha[ln][k][hd];
        uint4 hv = *(const uint4*)(h16 + (long)srcn[k] * C2 + c8);
        a0 += al * lo16f(hv.x); a1 += al * hi16f(hv.x);
        a2 += al * lo16f(hv.y); a3 += al * hi16f(hv.y);
        a4 += al * lo16f(hv.z); a5 += al * hi16f(hv.z);
        a6 += al * lo16f(hv.w); a7 += al * hi16f(hv.w);
    }
    float acc8[8] = {a0,a1,a2,a3,a4,a5,a6,a7};
    float4 res0 = *(const float4*)(xf + (long)n * C2 + c8);
    float4 res1 = *(const float4*)(xf + (long)n * C2 + c8 + 4);
    float res[8] = {res0.x,res0.y,res0.z,res0.w,res1.x,res1.y,res1.z,res1.w};
    float out[8];
    ushort4 o16a, o16b;
    unsigned short* po = (unsigned short*)&o16a;
#pragma unroll
    for (int q = 0; q < 8; ++q) {
        int c = c8 + q;
        float sc = gamma[c] * rsqrtf(var[c] + 1e-5f);
        float g = (acc8[q] + bias[c] - mean[c]) * sc + beta[c];
        g = fmaxf(g, 0.f) + res[q];
        out[q] = g;
    }
    o16a.x = f2b(out[0]); o16a.y = f2b(out[1]); o16a.z = f2b(out[2]); o16a.w = f2b(out[3]);
    o16b.x = f2b(out[4]); o16b.y = f2b(out[5]); o16b.z = f2b(out[6]); o16b.w = f2b(out[7]);
    *(float4*)(xf + (long)n * C2 + c8)     = make_float4(out[0],out[1],out[2],out[3]);
    *(float4*)(xf + (long)n * C2 + c8 + 4) = make_float4(out[4],out[5],out[6],out[7]);
    *(ushort4*)(xf16 + (long)n * C2 + c8)     = o16a;
    *(ushort4*)(xf16 + (long)n * C2 + c8 + 4) = o16b;
    (void)po;
}

// ---------------------------------------------------------------------------
// SE: channel sums over bf16 y (atomic partials), then the two tiny FC layers.
// ---------------------------------------------------------------------------
__global__ __launch_bounds__(256) void se_mean_kernel(
    const unsigned short* __restrict__ y16, float* __restrict__ means)
{
    const int b = blockIdx.x;
    const int t = threadIdx.x;
    float acc = 0.f;
    const int nb = b * 100;
    for (int nrel = 0; nrel < 100; ++nrel) acc += b2f(y16[(long)(nb + nrel) * C2 + t]);
    atomicAdd(&means[t], acc);
}

__global__ __launch_bounds__(256) void se_vec_kernel(
    const float* __restrict__ means,
    const float* __restrict__ se_w1, const float* __restrict__ se_b1,
    const float* __restrict__ se_w2, const float* __restrict__ se_b2,
    float* __restrict__ svec)
{
    __shared__ float mv[256];
    __shared__ float hv[64];
    const int t = threadIdx.x;
    mv[t] = means[t] * (1.0f / 25600.0f);
    __syncthreads();
    if (t < 64) {
        float s = se_b1[t];
        for (int cc = 0; cc < 256; ++cc) s += se_w1[t * 256 + cc] * mv[cc];
        hv[t] = fmaxf(s, 0.f);
    }
    __syncthreads();
    float s = se_b2[t];
    for (int k = 0; k < 64; ++k) s += se_w2[t * 64 + k] * hv[k];
    svec[t] = 1.0f / (1.0f + __expf(-s));
}

// ---------------------------------------------------------------------------
// Final: out[c][n] = y[n][c]*s[c] + id[n][c]  (LDS-transposed; dtype by flag)
// ---------------------------------------------------------------------------
__global__ __launch_bounds__(256) void final_kernel(
    const unsigned short* __restrict__ y16,
    const unsigned short* __restrict__ idb16,
    const float* __restrict__ svec,
    void* __restrict__ outp,
    const int* __restrict__ flag)
{
    __shared__ float T[64][65];
    const bool f32o = (*flag != 0);
    const int t = threadIdx.x;
    const int n0 = blockIdx.x * 64, c0 = blockIdx.y * 64;
#pragma unroll
    for (int it = 0; it < 16; ++it) {
        int e = t + it * 256;
        int nn = e >> 6, cc = e & 63;
        long idx = (long)(n0 + nn) * C2 + c0 + cc;
        T[cc][nn] = b2f(y16[idx]) * svec[c0 + cc] + b2f(idb16[idx]);
    }
    __syncthreads();
#pragma unroll
    for (int it = 0; it < 16; ++it) {
        int e = t + it * 256;
        int cc = e >> 6, nn = e & 63;
        long idx = (long)(c0 + cc) * NN + n0 + nn;
        float v = T[cc][nn];
        if (f32o) ((float*)outp)[idx] = v;
        else      ((unsigned short*)outp)[idx] = f2b(v);
    }
}

extern "C" void kernel_launch(void* const* d_in, const int* in_sizes, int n_in,
                              void* d_out, int out_size, void* d_ws, size_t ws_size,
                              hipStream_t stream) {
    float* ws = (float*)d_ws;
    float* cvt   = ws;                          // S_END small fp32 params
    float* xf    = ws + ((S_END + 63) & ~63);   // 6.5536M fp32 residual stream
    float* als   = xf + 6553600;                // 25600*8
    float* ald   = als + 204800;
    float* means = ald + 204800;                // 256
    float* svec  = means + 256;
    int*   flag  = (int*)(svec + 256);
    unsigned short* wb16  = (unsigned short*)(svec + 512);  // 262144 ushorts
    unsigned short* xT16  = wb16 + B_WEND;                  // 25600*128
    unsigned short* xf16  = xT16 + NN * 128;                // 25600*256
    unsigned short* h16   = xf16 + NN * 256;                // 25600*256 (h, then y)
    unsigned short* idb16 = h16 + NN * 256;                 // 25600*256

    const float* a_src_c = cvt + S_ASRC;
    const float* a_dst_c = cvt + S_ADST;
    const float* gbias_c = cvt + S_GBIAS;
    const float* bng_c   = cvt + S_BNG;
    const float* bnb_c   = cvt + S_BNB;
    const float* bnm_c   = cvt + S_BNM;
    const float* bnv_c   = cvt + S_BNV;
    const float* sew1_c  = cvt + S_SEW1;
    const float* seb1_c  = cvt + S_SEB1;
    const float* sew2_c  = cvt + S_SEW2;
    const float* seb2_c  = cvt + S_SEB2;

    hipMemsetAsync(means, 0, 256 * sizeof(float), stream);

    dim3 b256(256);
    dim3 gmfma(NN / 128, C2 / 64);     // 200 x 4
    dim3 gfin(NN / 64, C2 / 64);       // 400 x 4

    detect_kernel<<<1, b256, 0, stream>>>((const unsigned short*)d_in[0], flag);
    convert_small_kernel<<<32, b256, 0, stream>>>(
        d_in[4], d_in[5], d_in[6], d_in[7], d_in[8], d_in[9], d_in[10],
        d_in[12], d_in[13], d_in[14], d_in[15], cvt, flag);
    prep_w_kernel<<<256, b256, 0, stream>>>(d_in[2], d_in[1], d_in[3], d_in[11], wb16, flag);
    transpose_x_kernel<<<NN / 64, b256, 0, stream>>>(d_in[0], xT16, flag);

    mfma_gemm_x2_kernel<<<gmfma, b256, 0, stream>>>(
        xT16, wb16 + B_WIN, wb16 + B_WID, xf, xf16, idb16);

    for (int l = 0; l < 2; ++l) {
        mfma_gemm_nn_kernel<<<gmfma, b256, 0, stream>>>(
            xf16, wb16 + B_WGAT + l * 65536, h16,
            a_src_c + l * 256, a_dst_c + l * 256, als, ald, 1);
        aggregate_kernel<<<NN / 8, b256, 0, stream>>>(h16, als, ald,
            gbias_c + l * 256, bng_c + l * 256, bnb_c + l * 256,
            bnm_c + l * 256, bnv_c + l * 256, xf, xf16);
    }

    mfma_gemm_nn_kernel<<<gmfma, b256, 0, stream>>>(
        xf16, wb16 + B_WOUT, h16, nullptr, nullptr, nullptr, nullptr, 0);
    se_mean_kernel<<<256, b256, 0, stream>>>(h16, means);
    se_vec_kernel<<<1, b256, 0, stream>>>(means, sew1_c, seb1_c, sew2_c, seb2_c, svec);
    final_kernel<<<gfin, b256, 0, stream>>>(h16, idb16, svec, d_out, flag);
}

// Round 5
// 258.069 us; speedup vs baseline: 1.9613x; 1.0619x over previous
//
#include <hip/hip_runtime.h>

#define NN 25600      // nodes = 160*160
#define HH 160
#define WW 160
#define C2 256

// ---- bf16 weight pack offsets (ushorts) ----
#define B_WIN   0
#define B_WID   32768
#define B_WGAT  65536      // 2 layers x 65536
#define B_WOUT  196608
#define B_WEND  262144

// ---- small fp32 param offsets inside cvt (floats) ----
#define C_BNA   0          // 2x256 BN scale
#define C_BNB   512        // 2x256 BN shift (bias/mean folded)
#define C_ASRC  1024       // 2x256
#define C_ADST  1536       // 2x256
#define C_SEW1  2048       // 64x256
#define C_SEB1  18432      // 64
#define C_SEW2  18496      // 256x64
#define C_SEB2  34880      // 256
#define C_END   35136

typedef __attribute__((ext_vector_type(8))) short bfrag;   // 8 bf16 (4 VGPRs)
typedef __attribute__((ext_vector_type(4))) float ffrag;   // 4 fp32 acc

__device__ __forceinline__ float b2f(unsigned short u) {
    union { unsigned int ui; float f; } v; v.ui = ((unsigned int)u) << 16; return v.f;
}
__device__ __forceinline__ unsigned short f2b(float f) {
    union { float f; unsigned int u; } v; v.f = f;
    unsigned int u = v.u;
    unsigned int r = (u + 0x7FFFu + ((u >> 16) & 1u)) >> 16;
    return (unsigned short)r;
}
__device__ __forceinline__ float lo16f(unsigned int w) {
    union { unsigned int ui; float f; } v; v.ui = w << 16; return v.f;
}
__device__ __forceinline__ float hi16f(unsigned int w) {
    union { unsigned int ui; float f; } v; v.ui = w & 0xFFFF0000u; return v.f;
}
// Wave-uniform dtype probe: reads first 512 halfwords of x. fp32 inputs make
// mantissa-low halfwords wild as bf16 (P(miss) ~ 1e-70).
__device__ __forceinline__ bool probe_f32(const unsigned short* __restrict__ x) {
    int l = threadIdx.x & 63;
    bool wild = false;
#pragma unroll
    for (int i = 0; i < 8; ++i) {
        float v = b2f(x[l * 8 + i]);
        wild |= !(fabsf(v) < 1e6f);
    }
    return __any(wild);
}
__device__ __forceinline__ float ldf(const void* p, long i, bool f32) {
    return f32 ? ((const float*)p)[i] : b2f(((const unsigned short*)p)[i]);
}

// ---------------------------------------------------------------------------
// prep: pack weights to bf16, fold BN constants, convert small params.
// ---------------------------------------------------------------------------
__global__ __launch_bounds__(256) void prep_kernel(
    const unsigned short* __restrict__ x,
    const void* pwin, const void* pwid, const void* pwgat, const void* pwout,
    const void* pasrc, const void* padst, const void* pgbias,
    const void* pbng, const void* pbnb, const void* pbnm, const void* pbnv,
    const void* psew1, const void* pseb1, const void* psew2, const void* pseb2,
    unsigned short* __restrict__ wb, float* __restrict__ cvt)
{
    const bool f32 = probe_f32(x);
    const int gid = blockIdx.x * 256 + threadIdx.x;
    const int stride = gridDim.x * 256;
    for (int i = gid; i < B_WEND; i += stride) {
        const void* s; int o;
        if      (i < B_WID)   { s = pwin;  o = i - B_WIN; }
        else if (i < B_WGAT)  { s = pwid;  o = i - B_WID; }
        else if (i < B_WOUT)  { s = pwgat; o = i - B_WGAT; }
        else                  { s = pwout; o = i - B_WOUT; }
        wb[i] = f32 ? f2b(((const float*)s)[o]) : ((const unsigned short*)s)[o];
    }
    for (int i = gid; i < 512; i += stride) {
        float sc = ldf(pbng, i, f32) * rsqrtf(ldf(pbnv, i, f32) + 1e-5f);
        cvt[C_BNA + i] = sc;
        cvt[C_BNB + i] = (ldf(pgbias, i, f32) - ldf(pbnm, i, f32)) * sc + ldf(pbnb, i, f32);
        cvt[C_ASRC + i] = ldf(pasrc, i, f32);
        cvt[C_ADST + i] = ldf(padst, i, f32);
    }
    for (int i = gid; i < 16384; i += stride) {
        cvt[C_SEW1 + i] = ldf(psew1, i, f32);
        cvt[C_SEW2 + i] = ldf(psew2, i, f32);
    }
    for (int i = gid; i < 64; i += stride)  cvt[C_SEB1 + i] = ldf(pseb1, i, f32);
    for (int i = gid; i < 256; i += stride) cvt[C_SEB2 + i] = ldf(pseb2, i, f32);
}

// ---------------------------------------------------------------------------
// Transpose x: [128][25600] channel-major (fp32 or bf16) -> bf16 [25600][128].
// ---------------------------------------------------------------------------
__global__ __launch_bounds__(256) void transpose_x_kernel(
    const void* __restrict__ xsrc, unsigned short* __restrict__ xT)
{
    __shared__ unsigned short T[64 * 136];
    const bool f32 = probe_f32((const unsigned short*)xsrc);
    const int t = threadIdx.x;
    const int n0 = blockIdx.x * 64;
    const int nl = t & 63;
#pragma unroll
    for (int i = 0; i < 32; ++i) {
        int c = i * 4 + (t >> 6);
        long idx = (long)c * NN + n0 + nl;
        unsigned short v = f32 ? f2b(((const float*)xsrc)[idx])
                               : ((const unsigned short*)xsrc)[idx];
        T[nl * 136 + c] = v;
    }
    __syncthreads();
#pragma unroll
    for (int i = 0; i < 4; ++i) {
        int n = t >> 2, c0 = (t & 3) * 32 + i * 8;
        uint4 v = *(const uint4*)&T[n * 136 + c0];
        *(uint4*)(xT + (long)(n0 + n) * 128 + c0) = v;
    }
}

// ---------------------------------------------------------------------------
// MFMA GEMM (dual-B, K=128): xf16=A@Wi^T, idb16=A@Wd^T (both bf16).
// ---------------------------------------------------------------------------
__global__ __launch_bounds__(256) void mfma_gemm_x2_kernel(
    const unsigned short* __restrict__ A16,
    const unsigned short* __restrict__ Wi16,
    const unsigned short* __restrict__ Wd16,
    unsigned short* __restrict__ xf16,
    unsigned short* __restrict__ idb16)
{
    __shared__ unsigned short As[128 * 40];
    __shared__ unsigned short Bi[64 * 40];
    __shared__ unsigned short Bd[64 * 40];
    const int tid = threadIdx.x;
    const int m0 = blockIdx.x * 128, o0 = blockIdx.y * 64;
    const int lane = tid & 63, wv = tid >> 6;
    const int wm = wv >> 1, wn = wv & 1;
    const int lr = lane & 15, quad = lane >> 4;

    ffrag ai[4][2], ad[4][2];
#pragma unroll
    for (int mt = 0; mt < 4; ++mt)
#pragma unroll
        for (int nt = 0; nt < 2; ++nt) { ai[mt][nt] = (ffrag){0,0,0,0}; ad[mt][nt] = (ffrag){0,0,0,0}; }

    for (int k0 = 0; k0 < 128; k0 += 32) {
#pragma unroll
        for (int c = tid; c < 512; c += 256) {
            int row = c >> 2, q = c & 3;
            uint4 v = *(const uint4*)(A16 + (long)(m0 + row) * 128 + k0 + q * 8);
            *(uint4*)&As[row * 40 + q * 8] = v;
        }
        {
            int row = tid >> 2, q = tid & 3;
            uint4 vi = *(const uint4*)(Wi16 + (long)(o0 + row) * 128 + k0 + q * 8);
            uint4 vd = *(const uint4*)(Wd16 + (long)(o0 + row) * 128 + k0 + q * 8);
            *(uint4*)&Bi[row * 40 + q * 8] = vi;
            *(uint4*)&Bd[row * 40 + q * 8] = vd;
        }
        __syncthreads();
        bfrag a[4], bi[2], bd[2];
#pragma unroll
        for (int mt = 0; mt < 4; ++mt)
            a[mt] = *(const bfrag*)&As[(wm * 64 + mt * 16 + lr) * 40 + quad * 8];
#pragma unroll
        for (int nt = 0; nt < 2; ++nt) {
            bi[nt] = *(const bfrag*)&Bi[(wn * 32 + nt * 16 + lr) * 40 + quad * 8];
            bd[nt] = *(const bfrag*)&Bd[(wn * 32 + nt * 16 + lr) * 40 + quad * 8];
        }
#pragma unroll
        for (int mt = 0; mt < 4; ++mt)
#pragma unroll
            for (int nt = 0; nt < 2; ++nt) {
                ai[mt][nt] = __builtin_amdgcn_mfma_f32_16x16x32_bf16(a[mt], bi[nt], ai[mt][nt], 0, 0, 0);
                ad[mt][nt] = __builtin_amdgcn_mfma_f32_16x16x32_bf16(a[mt], bd[nt], ad[mt][nt], 0, 0, 0);
            }
        __syncthreads();
    }
#pragma unroll
    for (int mt = 0; mt < 4; ++mt)
#pragma unroll
        for (int nt = 0; nt < 2; ++nt)
#pragma unroll
            for (int r = 0; r < 4; ++r) {
                int m = m0 + wm * 64 + mt * 16 + quad * 4 + r;
                int o = o0 + wn * 32 + nt * 16 + lr;
                xf16[(long)m * C2 + o]  = f2b(ai[mt][nt][r]);
                idb16[(long)m * C2 + o] = f2b(ad[mt][nt][r]);
            }
}

// ---------------------------------------------------------------------------
// MFMA GEMM (K=256): C16 = A@W^T (bf16).
// mode 1: emit al_s/al_d from fp32 accumulators (attn epilogue).
// mode 2: atomic column sums into means (SE epilogue).
// ---------------------------------------------------------------------------
__global__ __launch_bounds__(256) void mfma_gemm_nn_kernel(
    const unsigned short* __restrict__ A16,
    const unsigned short* __restrict__ W16,
    unsigned short* __restrict__ C16,
    const float* __restrict__ asrc, const float* __restrict__ adst,
    float* __restrict__ al_s, float* __restrict__ al_d,
    float* __restrict__ means,
    int mode)
{
    __shared__ unsigned short As[128 * 40];
    __shared__ unsigned short Bs[64 * 40];
    const int tid = threadIdx.x;
    const int m0 = blockIdx.x * 128, o0 = blockIdx.y * 64;
    const int lane = tid & 63, wv = tid >> 6;
    const int wm = wv >> 1, wn = wv & 1;
    const int lr = lane & 15, quad = lane >> 4;

    ffrag acc[4][2];
#pragma unroll
    for (int mt = 0; mt < 4; ++mt)
#pragma unroll
        for (int nt = 0; nt < 2; ++nt) acc[mt][nt] = (ffrag){0,0,0,0};

    for (int k0 = 0; k0 < 256; k0 += 32) {
#pragma unroll
        for (int c = tid; c < 512; c += 256) {
            int row = c >> 2, q = c & 3;
            uint4 v = *(const uint4*)(A16 + (long)(m0 + row) * 256 + k0 + q * 8);
            *(uint4*)&As[row * 40 + q * 8] = v;
        }
        {
            int row = tid >> 2, q = tid & 3;
            uint4 v = *(const uint4*)(W16 + (long)(o0 + row) * 256 + k0 + q * 8);
            *(uint4*)&Bs[row * 40 + q * 8] = v;
        }
        __syncthreads();
        bfrag a[4], b[2];
#pragma unroll
        for (int mt = 0; mt < 4; ++mt)
            a[mt] = *(const bfrag*)&As[(wm * 64 + mt * 16 + lr) * 40 + quad * 8];
#pragma unroll
        for (int nt = 0; nt < 2; ++nt)
            b[nt] = *(const bfrag*)&Bs[(wn * 32 + nt * 16 + lr) * 40 + quad * 8];
#pragma unroll
        for (int mt = 0; mt < 4; ++mt)
#pragma unroll
            for (int nt = 0; nt < 2; ++nt)
                acc[mt][nt] = __builtin_amdgcn_mfma_f32_16x16x32_bf16(a[mt], b[nt], acc[mt][nt], 0, 0, 0);
        __syncthreads();
    }
#pragma unroll
    for (int mt = 0; mt < 4; ++mt)
#pragma unroll
        for (int nt = 0; nt < 2; ++nt)
#pragma unroll
            for (int r = 0; r < 4; ++r) {
                int m = m0 + wm * 64 + mt * 16 + quad * 4 + r;
                int o = o0 + wn * 32 + nt * 16 + lr;
                C16[(long)m * C2 + o] = f2b(acc[mt][nt][r]);
            }
    if (mode == 1) {
        const int head = blockIdx.y * 2 + wn;
        const float as0 = asrc[head * 32 + lr], as1 = asrc[head * 32 + 16 + lr];
        const float ad0 = adst[head * 32 + lr], ad1 = adst[head * 32 + 16 + lr];
#pragma unroll
        for (int mt = 0; mt < 4; ++mt)
#pragma unroll
            for (int r = 0; r < 4; ++r) {
                float ps = acc[mt][0][r] * as0 + acc[mt][1][r] * as1;
                float pd = acc[mt][0][r] * ad0 + acc[mt][1][r] * ad1;
#pragma unroll
                for (int sh = 1; sh < 16; sh <<= 1) {
                    ps += __shfl_xor(ps, sh);
                    pd += __shfl_xor(pd, sh);
                }
                if (lr == 0) {
                    int m = m0 + wm * 64 + mt * 16 + quad * 4 + r;
                    al_s[m * 8 + head] = ps;
                    al_d[m * 8 + head] = pd;
                }
            }
    } else if (mode == 2) {
        // column partial sums over this block's 128 rows -> means atomics
#pragma unroll
        for (int nt = 0; nt < 2; ++nt) {
            float p = 0.f;
#pragma unroll
            for (int mt = 0; mt < 4; ++mt)
#pragma unroll
                for (int r = 0; r < 4; ++r) p += acc[mt][nt][r];
            p += __shfl_xor(p, 16);
            p += __shfl_xor(p, 32);
            if (quad == 0) atomicAdd(&means[o0 + wn * 32 + nt * 16 + lr], p);
        }
    }
}

// ---------------------------------------------------------------------------
// Aggregation: 8 nodes/block, 32 thr/node, 8 bf16 channels/thread.
// Softmax once per (node,head) in LDS; 11-tap weighted gather of bf16 h;
// folded BN (A,B) + ReLU + bf16 residual. Writes xf16 in place.
// ---------------------------------------------------------------------------
__global__ __launch_bounds__(256) void aggregate_kernel(
    const unsigned short* __restrict__ h16,
    const float* __restrict__ al_s,
    const float* __restrict__ al_d,
    const float* __restrict__ bnA,
    const float* __restrict__ bnB,
    unsigned short* __restrict__ xf16)
{
    const int SI[11] = { 1, 1, 1, 0, 0, -1, -1, -1, -2,  0, 0};
    const int SJ[11] = { 1, 0,-1, 1,-1,  1,  0, -1,  0, -2, 0};
    __shared__ float es[8][11][8];
    __shared__ float alpha[8][11][8];

    const int t = threadIdx.x;
    const int ln = t >> 5;            // local node 0..7
    const int l = t & 31;
    const int n = blockIdx.x * 8 + ln;
    const int i = n / WW, j = n % WW;

    for (int idx = t; idx < 704; idx += 256) {
        int lln = idx / 88, rem = idx - lln * 88;
        int k = rem >> 3, hh = rem & 7;
        int nn2 = blockIdx.x * 8 + lln;
        int ii = nn2 / WW, jj = nn2 - ii * WW;
        int si = ii + SI[k], sj = jj + SJ[k];
        bool okk = (si >= 0) & (si < HH) & (sj >= 0) & (sj < WW);
        es[lln][k][hh] = okk ? al_s[(si * WW + sj) * 8 + hh] : -1e30f;
    }
    __syncthreads();

    if (l < 8) {
        const int hd = l;
        const float ald = al_d[n * 8 + hd];
        float e[11];
        float mx = -1e30f;
#pragma unroll
        for (int k = 0; k < 11; ++k) {
            float v = es[ln][k][hd] + ald;
            v = v > 0.f ? v : 0.2f * v;          // leaky_relu(0.2)
            e[k] = v;
            mx = fmaxf(mx, v);
        }
        float denom = 0.f;
#pragma unroll
        for (int k = 0; k < 11; ++k) {
            float p = __expf(e[k] - mx);
            e[k] = p;
            denom += p;
        }
        const float inv = 1.f / (denom + 1e-16f);
#pragma unroll
        for (int k = 0; k < 11; ++k) alpha[ln][k][hd] = e[k] * inv;
    }
    __syncthreads();

    const int c8 = l * 8;
    const int hd = l >> 2;
    int srcn[11];
#pragma unroll
    for (int k = 0; k < 11; ++k) {
        int si = i + SI[k], sj = j + SJ[k];
        bool ok = (si >= 0) & (si < HH) & (sj >= 0) & (sj < WW);
        srcn[k] = ok ? si * WW + sj : n;
    }
    float a0=0.f,a1=0.f,a2=0.f,a3=0.f,a4=0.f,a5=0.f,a6=0.f,a7=0.f;
#pragma unroll
    for (int k = 0; k < 11; ++k) {
        float al = alpha[ln][k][hd];
        uint4 hv = *(const uint4*)(h16 + (long)srcn[k] * C2 + c8);
        a0 += al * lo16f(hv.x); a1 += al * hi16f(hv.x);
        a2 += al * lo16f(hv.y); a3 += al * hi16f(hv.y);
        a4 += al * lo16f(hv.z); a5 += al * hi16f(hv.z);
        a6 += al * lo16f(hv.w); a7 += al * hi16f(hv.w);
    }
    float acc8[8] = {a0,a1,a2,a3,a4,a5,a6,a7};
    uint4 rv = *(const uint4*)(xf16 + (long)n * C2 + c8);
    float res[8] = {lo16f(rv.x),hi16f(rv.x),lo16f(rv.y),hi16f(rv.y),
                    lo16f(rv.z),hi16f(rv.z),lo16f(rv.w),hi16f(rv.w)};
    ushort4 o16a, o16b;
    float out[8];
#pragma unroll
    for (int q = 0; q < 8; ++q) {
        int c = c8 + q;
        float g = acc8[q] * bnA[c] + bnB[c];
        out[q] = fmaxf(g, 0.f) + res[q];
    }
    o16a.x = f2b(out[0]); o16a.y = f2b(out[1]); o16a.z = f2b(out[2]); o16a.w = f2b(out[3]);
    o16b.x = f2b(out[4]); o16b.y = f2b(out[5]); o16b.z = f2b(out[6]); o16b.w = f2b(out[7]);
    *(ushort4*)(xf16 + (long)n * C2 + c8)     = o16a;
    *(ushort4*)(xf16 + (long)n * C2 + c8 + 4) = o16b;
}

// ---------------------------------------------------------------------------
// Final: compute SE vector from means (redundant per block, L2-resident
// weights), then out[c][n] = y[n][c]*s[c] + id[n][c] (transposed store).
// ---------------------------------------------------------------------------
__global__ __launch_bounds__(256) void final_kernel(
    const unsigned short* __restrict__ x_probe,
    const unsigned short* __restrict__ y16,
    const unsigned short* __restrict__ idb16,
    const float* __restrict__ means,
    const float* __restrict__ cvt,
    void* __restrict__ outp)
{
    __shared__ float T[64][65];
    __shared__ float mv[256];
    __shared__ float hv[64];
    __shared__ float sv[64];
    const bool f32o = probe_f32(x_probe);
    const int t = threadIdx.x;
    const int n0 = blockIdx.x * 64, c0 = blockIdx.y * 64;

    mv[t] = means[t] * (1.0f / 25600.0f);
    __syncthreads();
    if (t < 64) {
        const float* w1 = cvt + C_SEW1 + t * 256;
        float s = cvt[C_SEB1 + t];
        for (int cc = 0; cc < 256; cc += 4) {
            float4 wv = *(const float4*)(w1 + cc);
            s += wv.x * mv[cc] + wv.y * mv[cc+1] + wv.z * mv[cc+2] + wv.w * mv[cc+3];
        }
        hv[t] = fmaxf(s, 0.f);
    }
    __syncthreads();
    if (t < 64) {
        const int c = c0 + t;
        const float* w2 = cvt + C_SEW2 + c * 64;
        float s = cvt[C_SEB2 + c];
        for (int k = 0; k < 64; k += 4) {
            float4 wv = *(const float4*)(w2 + k);
            s += wv.x * hv[k] + wv.y * hv[k+1] + wv.z * hv[k+2] + wv.w * hv[k+3];
        }
        sv[t] = 1.0f / (1.0f + __expf(-s));
    }
    __syncthreads();
#pragma unroll
    for (int it = 0; it < 16; ++it) {
        int e = t + it * 256;
        int nn = e >> 6, cc = e & 63;
        long idx = (long)(n0 + nn) * C2 + c0 + cc;
        T[cc][nn] = b2f(y16[idx]) * sv[cc] + b2f(idb16[idx]);
    }
    __syncthreads();
#pragma unroll
    for (int it = 0; it < 16; ++it) {
        int e = t + it * 256;
        int cc = e >> 6, nn = e & 63;
        long idx = (long)(c0 + cc) * NN + n0 + nn;
        float v = T[cc][nn];
        if (f32o) ((float*)outp)[idx] = v;
        else      ((unsigned short*)outp)[idx] = f2b(v);
    }
}

extern "C" void kernel_launch(void* const* d_in, const int* in_sizes, int n_in,
                              void* d_out, int out_size, void* d_ws, size_t ws_size,
                              hipStream_t stream) {
    float* ws = (float*)d_ws;
    float* cvt   = ws;                          // C_END small fp32 params
    float* als   = ws + ((C_END + 63) & ~63);   // 25600*8
    float* ald   = als + 204800;
    float* means = ald + 204800;                // 256
    unsigned short* wb16  = (unsigned short*)(means + 256);  // 262144
    unsigned short* xT16  = wb16 + B_WEND;                   // 25600*128
    unsigned short* xf16  = xT16 + NN * 128;                 // 25600*256 (residual stream)
    unsigned short* h16   = xf16 + NN * 256;                 // 25600*256 (h, then y)
    unsigned short* idb16 = h16 + NN * 256;                  // 25600*256

    const unsigned short* xp = (const unsigned short*)d_in[0];

    hipMemsetAsync(means, 0, 256 * sizeof(float), stream);

    dim3 b256(256);
    dim3 gmfma(NN / 128, C2 / 64);     // 200 x 4
    dim3 gfin(NN / 64, C2 / 64);       // 400 x 4

    prep_kernel<<<256, b256, 0, stream>>>(
        xp, d_in[2], d_in[1], d_in[3], d_in[11],
        d_in[4], d_in[5], d_in[6], d_in[7], d_in[8], d_in[9], d_in[10],
        d_in[12], d_in[13], d_in[14], d_in[15], wb16, cvt);
    transpose_x_kernel<<<NN / 64, b256, 0, stream>>>(d_in[0], xT16);

    mfma_gemm_x2_kernel<<<gmfma, b256, 0, stream>>>(
        xT16, wb16 + B_WIN, wb16 + B_WID, xf16, idb16);

    for (int l = 0; l < 2; ++l) {
        mfma_gemm_nn_kernel<<<gmfma, b256, 0, stream>>>(
            xf16, wb16 + B_WGAT + l * 65536, h16,
            cvt + C_ASRC + l * 256, cvt + C_ADST + l * 256, als, ald, nullptr, 1);
        aggregate_kernel<<<NN / 8, b256, 0, stream>>>(h16, als, ald,
            cvt + C_BNA + l * 256, cvt + C_BNB + l * 256, xf16);
    }

    mfma_gemm_nn_kernel<<<gmfma, b256, 0, stream>>>(
        xf16, wb16 + B_WOUT, h16, nullptr, nullptr, nullptr, nullptr, means, 2);
    final_kernel<<<gfin, b256, 0, stream>>>(xp, h16, idb16, means, cvt, d_out);
}